// Round 14
// baseline (14660.675 us; speedup 1.0000x reference)
//
#include <hip/hip_runtime.h>
#include <hip/hip_fp16.h>

#define Tt 1024
#define Ii 256
#define Hh 512
#define Cc 10

typedef _Float16 f16;
typedef _Float16 f16x8 __attribute__((ext_vector_type(8)));
typedef _Float16 f16x4 __attribute__((ext_vector_type(4)));
typedef _Float16 f16x2 __attribute__((ext_vector_type(2)));
typedef float    f32x4 __attribute__((ext_vector_type(4)));

static __device__ __forceinline__ f32x4 mfma16(f16x8 a, f16x8 b, f32x4 c) {
  return __builtin_amdgcn_mfma_f32_16x16x32_f16(a, b, c, 0, 0, 0);
}
static __device__ __forceinline__ float fast_tanh(float v) {
  float e = __expf(2.0f * v);
  return 1.0f - 2.0f / (e + 1.0f);
}
#define LBAR() do { asm volatile("s_waitcnt lgkmcnt(0)" ::: "memory"); \
                    __builtin_amdgcn_s_barrier(); \
                    __builtin_amdgcn_sched_barrier(0); } while (0)

// ---- ws static offsets (bytes) ----
#define OFF_WT1 0u         // f16 wt_ih1 frag [8 kc][4 grp][512 col][8]   (256 KB)
#define OFF_WT2 262144u    // f16 wt_ih2 frag [16][4][512][8]             (512 KB)
#define OFF_WH1 786432u    // f16 w_hh1 row-major [512][512]              (512 KB)
#define OFF_WH2 1310720u   // f16 w_hh2 row-major [512][512]              (512 KB)
#define OFF_H1S 1835008u   // f16 h1 state [8 bg][16][512]                (128 KB)
#define OFF_H2S 1966080u   // f16 h2 state                                (128 KB)
#define OFF_DYN 2097152u   // chunk buffers: xw | h1 | par, each CC*131072 B

// ============ K0: weight prep (fp32 -> f16, frag + row-major) ============
__global__ void k0_prep(const float* __restrict__ w_ih1, const float* __restrict__ w_ih2,
                        const float* __restrict__ w_hh1, const float* __restrict__ w_hh2,
                        char* __restrict__ ws) {
  f16* wt1 = (f16*)(ws + OFF_WT1);
  f16* wt2 = (f16*)(ws + OFF_WT2);
  f16* wh1 = (f16*)(ws + OFF_WH1);
  f16* wh2 = (f16*)(ws + OFF_WH2);
  const int i = blockIdx.x * 512 + threadIdx.x;   // 512x512 elements
  const int c = i >> 9, k = i & 511;
  wh1[i] = (f16)w_hh1[i];
  wh2[i] = (f16)w_hh2[i];
  const int kc = k >> 5, grp = (k >> 3) & 3, j = k & 7;
  wt2[((size_t)(kc * 4 + grp) * 512 + c) * 8 + j] = (f16)w_ih2[i];
  if (k < 256)
    wt1[((size_t)(kc * 4 + grp) * 512 + c) * 8 + j] = (f16)w_ih1[c * 256 + k];
}

// ============ K1: xw chunk GEMM: xw_t = x_t @ w_ih1^T + (b_ih1+b_hh1) ============
__global__ __launch_bounds__(256) void k1_xw(
    const float* __restrict__ x, const f16* __restrict__ wt1,
    const float* __restrict__ b_ih1, const float* __restrict__ b_hh1,
    f16* __restrict__ xwb, int t0)
{
  const int tl = blockIdx.x >> 3, bg = blockIdx.x & 7;
  const int t = t0 + tl;
  const int tid = threadIdx.x, wid = tid >> 6, lane = tid & 63;
  const int lm = lane & 15, lgrp = lane >> 4, lk8 = lgrp * 8;
  const int wcol0 = wid * 128;

  f32x4 acc[8];
  #pragma unroll
  for (int nt = 0; nt < 8; ++nt) {
    const int col = wcol0 + nt * 16 + lm;
    const float b = b_ih1[col] + b_hh1[col];
    acc[nt] = f32x4{b, b, b, b};
  }
  const float* xr = x + ((size_t)(bg * 16 + lm) * Tt + t) * Ii + lk8;
  #pragma unroll
  for (int kc = 0; kc < 8; ++kc) {
    float4 a = *(const float4*)(xr + kc * 32);
    float4 b = *(const float4*)(xr + kc * 32 + 4);
    f16x8 A{(f16)a.x,(f16)a.y,(f16)a.z,(f16)a.w,(f16)b.x,(f16)b.y,(f16)b.z,(f16)b.w};
    #pragma unroll
    for (int nt = 0; nt < 8; ++nt)
      acc[nt] = mfma16(A, *(const f16x8*)&wt1[((size_t)(kc * 4 + lgrp) * 512 + wcol0 + nt * 16 + lm) * 8], acc[nt]);
  }
  f16* dst = xwb + ((size_t)tl * 8 + bg) * 8192;
  #pragma unroll
  for (int nt = 0; nt < 8; ++nt)
    *(f16x4*)(dst + (wid * 8 + nt) * 256 + lm * 16 + lgrp * 4) =
      f16x4{(f16)acc[nt][0], (f16)acc[nt][1], (f16)acc[nt][2], (f16)acc[nt][3]};
}

// ============ K3: par chunk GEMM: par_t = h1_t @ w_ih2^T + (b_ih2+b_hh2) ============
__global__ __launch_bounds__(256) void k3_par(
    const f16* __restrict__ h1b, const f16* __restrict__ wt2,
    const float* __restrict__ b_ih2, const float* __restrict__ b_hh2,
    f16* __restrict__ parb)
{
  __shared__ __align__(16) f16 sA[16 * 520];
  const int tl = blockIdx.x >> 3, bg = blockIdx.x & 7;
  const int tid = threadIdx.x, wid = tid >> 6, lane = tid & 63;
  const int lm = lane & 15, lgrp = lane >> 4, lk8 = lgrp * 8;
  const int wcol0 = wid * 128;

  const f16* hs = h1b + ((size_t)tl * 8 + bg) * 8192;
  for (int i = tid; i < 1024; i += 256) {
    const int row = i >> 6, c8 = (i & 63) * 8;
    *(f16x8*)&sA[row * 520 + c8] = *(const f16x8*)&hs[row * 512 + c8];
  }
  f32x4 acc[8];
  #pragma unroll
  for (int nt = 0; nt < 8; ++nt) {
    const int col = wcol0 + nt * 16 + lm;
    const float b = b_ih2[col] + b_hh2[col];
    acc[nt] = f32x4{b, b, b, b};
  }
  __syncthreads();
  #pragma unroll
  for (int kc = 0; kc < 16; ++kc) {
    f16x8 A = *(const f16x8*)&sA[lm * 520 + kc * 32 + lk8];
    #pragma unroll
    for (int nt = 0; nt < 8; ++nt)
      acc[nt] = mfma16(A, *(const f16x8*)&wt2[((size_t)(kc * 4 + lgrp) * 512 + wcol0 + nt * 16 + lm) * 8], acc[nt]);
  }
  f16* dst = parb + ((size_t)tl * 8 + bg) * 8192;
  #pragma unroll
  for (int nt = 0; nt < 8; ++nt)
    *(f16x4*)(dst + (wid * 8 + nt) * 256 + lm * 16 + lgrp * 4) =
      f16x4{(f16)acc[nt][0], (f16)acc[nt][1], (f16)acc[nt][2], (f16)acc[nt][3]};
}

// ============ K2/K4: recurrence chain chunk (8 blocks, state in LDS) ============
// h_p = tanh(feed_p + h_{p-1} @ W^T).  B fully CU-resident:
// kc0-3 LDS, kc4-11 AGPR (256, "+a" pinned), kc12-15 VGPR (128, "+v" pinned).
__global__ __launch_bounds__(256) __attribute__((amdgpu_waves_per_eu(1, 1)))
void k_chain(const f16* __restrict__ whf,      // [512][512] row-major
             const f16* __restrict__ feed,     // [CC][8][32 tiles][256] frag-major
             f16* __restrict__ hstate,         // [8][16][512]
             f16* __restrict__ hbuf,           // [CC][8][16][512] or nullptr
             const float* __restrict__ w_out, const float* __restrict__ b_out,
             float* __restrict__ out,
             int t0, int CC)
{
  __shared__ __align__(16) f16 sB[4 * 4 * 512 * 8];   // 128 KB, kc0-3 frag layout
  __shared__ __align__(16) f16 sH[16 * 520];          // state
  unsigned* sH32 = (unsigned*)sH;
  const int bg = blockIdx.x;
  const int tid = threadIdx.x, wid = tid >> 6, lane = tid & 63;
  const int lm = lane & 15, lgrp = lane >> 4, lk8 = lgrp * 8;
  const int rlo = (lane & 1) * 2;
  const int wcol0 = wid * 128;

  // stage sB (kc0-3)
  for (int i = tid; i < 8192; i += 256) {
    const int kc = i >> 11, grp = (i >> 9) & 3, col = i & 511;
    *(f16x8*)&sB[(size_t)i * 8] = *(const f16x8*)&whf[(size_t)col * 512 + kc * 32 + grp * 8];
  }
  // state init/load
  if (t0 == 0) {
    for (int i = tid; i < 16 * 260; i += 256) sH32[i] = 0u;
  } else {
    const unsigned* hsg = (const unsigned*)(hstate + (size_t)bg * 16 * 512);
    for (int i = tid; i < 16 * 256; i += 256)
      sH32[(i >> 8) * 260 + (i & 255)] = hsg[i];
  }
  // AGPR pins: kc4-11 (8 kc x 8 nt x 4 regs = 256 AGPR)
  f16x8 wbA[8][8];
  #pragma unroll
  for (int kr = 0; kr < 8; ++kr)
    #pragma unroll
    for (int nt = 0; nt < 8; ++nt) {
      wbA[kr][nt] = *(const f16x8*)&whf[(size_t)(wcol0 + nt * 16 + lm) * 512 + (kr + 4) * 32 + lk8];
      asm volatile("" : "+a"(wbA[kr][nt]));
    }
  // VGPR pins: kc12-15 (4 kc x 8 nt x 4 = 128 VGPR)
  f16x8 wbV[4][8];
  #pragma unroll
  for (int kr = 0; kr < 4; ++kr)
    #pragma unroll
    for (int nt = 0; nt < 8; ++nt) {
      wbV[kr][nt] = *(const f16x8*)&whf[(size_t)(wcol0 + nt * 16 + lm) * 512 + (kr + 12) * 32 + lk8];
      asm volatile("" : "+v"(wbV[kr][nt]));
    }
  __syncthreads();

  for (int p = 0; p < CC; ++p) {
    // feed loads (plain; latency hides under MFMA phase)
    const f16* fin = feed + ((size_t)p * 8 + bg) * 8192;
    f16x4 fv[8];
    #pragma unroll
    for (int nt = 0; nt < 8; ++nt)
      fv[nt] = *(const f16x4*)(fin + (wid * 8 + nt) * 256 + lm * 16 + lgrp * 4);

    f32x4 acc[8];
    #pragma unroll
    for (int nt = 0; nt < 8; ++nt) acc[nt] = f32x4{0.f, 0.f, 0.f, 0.f};
    if (t0 + p > 0) {
      #pragma unroll
      for (int kc = 0; kc < 16; ++kc) {
        f16x8 A = *(const f16x8*)&sH[lm * 520 + kc * 32 + lk8];
        #pragma unroll
        for (int nt = 0; nt < 8; ++nt) {
          f16x8 B;
          if (kc < 4)       B = *(const f16x8*)&sB[((size_t)(kc * 4 + lgrp) * 512 + wcol0 + nt * 16 + lm) * 8];
          else if (kc < 12) B = wbA[kc - 4][nt];
          else              B = wbV[kc - 12][nt];
          acc[nt] = mfma16(A, B, acc[nt]);
        }
      }
    }
    LBAR();   // all state reads done before overwrite

    #pragma unroll
    for (int nt = 0; nt < 8; ++nt) {
      acc[nt][0] += (float)fv[nt][0]; acc[nt][1] += (float)fv[nt][1];
      acc[nt][2] += (float)fv[nt][2]; acc[nt][3] += (float)fv[nt][3];
    }

    unsigned* hb32 = nullptr;
    if (hbuf) hb32 = (unsigned*)(hbuf + ((size_t)p * 8 + bg) * 8192);
    #pragma unroll
    for (int nt = 0; nt < 8; ++nt) {
      const int cp = (wcol0 + nt * 16 + lm) >> 1;
      float v0 = fast_tanh(acc[nt][0]), v1 = fast_tanh(acc[nt][1]);
      float v2 = fast_tanh(acc[nt][2]), v3 = fast_tanh(acc[nt][3]);
      float o0 = __shfl_xor(v0, 1, 64), o1 = __shfl_xor(v1, 1, 64);
      float o2 = __shfl_xor(v2, 1, 64), o3 = __shfl_xor(v3, 1, 64);
      float m[4] = {v0, v1, v2, v3}, q[4] = {o0, o1, o2, o3};
      #pragma unroll
      for (int r2 = 0; r2 < 2; ++r2) {
        const int rr = rlo + r2, row = lgrp * 4 + rr;
        float ve = (lane & 1) ? q[rr] : m[rr];
        float vo = (lane & 1) ? m[rr] : q[rr];
        union { f16x2 h; unsigned u; } P; P.h = f16x2{(f16)ve, (f16)vo};
        sH32[row * 260 + cp] = P.u;
        if (hb32) hb32[row * 256 + cp] = P.u;   // plain async store; no fence
      }
    }
    LBAR();   // state writes visible for next step
  }

  // save state for next chunk
  {
    unsigned* hsg = (unsigned*)(hstate + (size_t)bg * 16 * 512);
    for (int i = tid; i < 16 * 256; i += 256)
      hsg[i] = sH32[(i >> 8) * 260 + (i & 255)];
  }

  // final output (h2 chain, last chunk only): out = h2_{T-1} @ w_out^T + b_out
  if (w_out && (t0 + CC == Tt)) {
    const int rl = wid * 4 + (lane >> 4);      // row 0..15
    const int l16 = lane & 15;
    const f16* hr = &sH[rl * 520 + l16 * 32];
    f16x8 a0 = *(const f16x8*)hr;
    f16x8 a1 = *(const f16x8*)(hr + 8);
    f16x8 a2 = *(const f16x8*)(hr + 16);
    f16x8 a3 = *(const f16x8*)(hr + 24);
    float hf[32];
    #pragma unroll
    for (int j = 0; j < 8; ++j) {
      hf[j] = (float)a0[j]; hf[8 + j] = (float)a1[j];
      hf[16 + j] = (float)a2[j]; hf[24 + j] = (float)a3[j];
    }
    #pragma unroll
    for (int c = 0; c < Cc; ++c) {
      const float* wr_ = w_out + (size_t)c * Hh + l16 * 32;
      float s = 0.f;
      #pragma unroll
      for (int j4 = 0; j4 < 8; ++j4) {
        float4 w4 = *(const float4*)(wr_ + j4 * 4);
        s += hf[j4*4]*w4.x + hf[j4*4+1]*w4.y + hf[j4*4+2]*w4.z + hf[j4*4+3]*w4.w;
      }
      #pragma unroll
      for (int off = 8; off >= 1; off >>= 1) s += __shfl_xor(s, off, 64);
      if (l16 == 0) out[(bg * 16 + rl) * Cc + c] = s + b_out[c];
    }
  }
}

extern "C" void kernel_launch(void* const* d_in, const int* in_sizes, int n_in,
                              void* d_out, int out_size, void* d_ws, size_t ws_size,
                              hipStream_t stream) {
  (void)in_sizes; (void)n_in; (void)out_size;
  const float* x     = (const float*)d_in[0];
  const float* w_ih1 = (const float*)d_in[1];
  const float* w_hh1 = (const float*)d_in[2];
  const float* b_ih1 = (const float*)d_in[3];
  const float* b_hh1 = (const float*)d_in[4];
  const float* w_ih2 = (const float*)d_in[5];
  const float* w_hh2 = (const float*)d_in[6];
  const float* b_ih2 = (const float*)d_in[7];
  const float* b_hh2 = (const float*)d_in[8];
  const float* w_out = (const float*)d_in[9];
  const float* b_out = (const float*)d_in[10];
  float* out = (float*)d_out;
  char* ws = (char*)d_ws;

  // pick largest chunk size whose 3 buffers fit ws
  int CCv = 256;
  while (CCv > 4 && (size_t)OFF_DYN + 3ull * (size_t)CCv * 131072ull > ws_size) CCv >>= 1;
  const int NC = Tt / CCv;

  const f16* wt1  = (const f16*)(ws + OFF_WT1);
  const f16* wt2  = (const f16*)(ws + OFF_WT2);
  const f16* wh1f = (const f16*)(ws + OFF_WH1);
  const f16* wh2f = (const f16*)(ws + OFF_WH2);
  f16* h1s = (f16*)(ws + OFF_H1S);
  f16* h2s = (f16*)(ws + OFF_H2S);
  f16* xwb  = (f16*)(ws + OFF_DYN);
  f16* h1b  = xwb + (size_t)CCv * 65536;
  f16* parb = h1b + (size_t)CCv * 65536;

  hipLaunchKernelGGL(k0_prep, dim3(512), dim3(512), 0, stream,
                     w_ih1, w_ih2, w_hh1, w_hh2, ws);
  for (int c = 0; c < NC; ++c) {
    const int t0 = c * CCv;
    hipLaunchKernelGGL(k1_xw, dim3(CCv * 8), dim3(256), 0, stream,
                       x, wt1, b_ih1, b_hh1, xwb, t0);
    hipLaunchKernelGGL(k_chain, dim3(8), dim3(256), 0, stream,
                       wh1f, xwb, h1s, h1b,
                       (const float*)nullptr, (const float*)nullptr, (float*)nullptr,
                       t0, CCv);
    hipLaunchKernelGGL(k3_par, dim3(CCv * 8), dim3(256), 0, stream,
                       h1b, wt2, b_ih2, b_hh2, parb);
    hipLaunchKernelGGL(k_chain, dim3(8), dim3(256), 0, stream,
                       wh2f, parb, h2s, (f16*)nullptr,
                       w_out, b_out, out, t0, CCv);
  }
}